// Round 6
// baseline (134.630 us; speedup 1.0000x reference)
//
#include <hip/hip_runtime.h>
#include <cmath>

#define Hn 512
#define Wn 512
#define Bn 32
#define SEGH 64                       // output rows per wave
#define NSEG (Hn / SEGH)              // 8
#define OUTW 56                       // output cols per wave (64 lanes - 2*4 halo)
#define STRIPS 10                     // ceil(512/56)
#define WPB 4                         // waves per 256-thread block
#define TOTWAVES (Bn * NSEG * STRIPS) // 2560
#define NBLK (TOTWAVES / WPB)         // 640

struct GaussW { float g[9]; };

// Barrier-free rolling separable conv. One wave owns a 56-wide x 64-tall
// output tile; horizontal 9-tap via in-wave bpermute shuffles (lanes carry
// a 64-wide strip incl. +-4 halo), vertical 9-tap via rolling register
// window (box) + 9 phase-rotating accumulators (gauss). No LDS, no barriers:
// avoids the ~60 workgroups/us dispatch ceiling that pinned R1/R5 at 134us
// (8192 short blocks) by using 640 long-lived blocks.
__global__ __launch_bounds__(256, 2) void fuse_loss_kernel(
    const float* __restrict__ vis, const float* __restrict__ ir,
    const float* __restrict__ fus, const float* __restrict__ mask,
    float* __restrict__ out, GaussW gw)
{
    const int lane = threadIdx.x & 63;
    const int wid  = blockIdx.x * WPB + (threadIdx.x >> 6);
    const int img   = wid / (NSEG * STRIPS);
    const int t2    = wid % (NSEG * STRIPS);
    const int yseg  = t2 / STRIPS;
    const int strip = t2 % STRIPS;

    const int Y0 = yseg * SEGH;
    const int xl = strip * OUTW - 4 + lane;           // column this lane loads
    const bool okx    = (unsigned)xl < (unsigned)Wn;
    const bool oklane = (lane >= 4) && (lane < 60) && okx;  // emitting lanes

    const size_t ibase = (size_t)img * ((size_t)Hn * Wn);
    const float* pir = ir  + ibase;
    const float* pvi = vis + ibase;
    const float* pfu = fus + ibase;
    const float* pmk = mask + ibase;

    // bpermute byte addresses for lane offsets -4..-1,+1..+4 (hoisted)
    int bpm[4], bpp[4];
    #pragma unroll
    for (int k = 1; k <= 4; ++k) {
        bpm[k-1] = ((lane - k) & 63) << 2;
        bpp[k-1] = ((lane + k) & 63) << 2;
    }

    // vertical state (all statically indexed via unrolled j/s)
    float ag_ir[9], ag_vi[9], ag_i2[9], ag_v2[9];   // gauss slot accumulators
    float hb_i[9], hb_v[9];                         // box 9-row history
    float Sb_i = 0.f, Sb_v = 0.f;                   // box rolling sums
    #pragma unroll
    for (int s = 0; s < 9; ++s) {
        ag_ir[s] = 0.f; ag_vi[s] = 0.f; ag_i2[s] = 0.f; ag_v2[s] = 0.f;
        hb_i[s] = 0.f; hb_v[s] = 0.f;
    }

    float acc = 0.f;
    const float g4 = gw.g[4], g8 = gw.g[8];

    for (int grp = 0; grp < (SEGH + 8) / 9; ++grp) {   // 8 groups x 9 rows = 72
        #pragma unroll
        for (int j = 0; j < 9; ++j) {
            const int r = grp * 9 + j;
            const int y = Y0 - 4 + r;
            const bool oky  = (unsigned)y < (unsigned)Hn;   // wave-uniform
            const bool emit = (r >= 8);                      // wave-uniform
            const int yo = y - 4;

            // issue mask load early; consumed ~150 VALU ops later
            float mkv = 0.f;
            if (emit && oklane) mkv = pmk[(size_t)yo * Wn + xl];

            float irv = 0.f, viv = 0.f, fuv = 0.f;
            if (oky && okx) {
                size_t o = (size_t)y * Wn + xl;
                irv = pir[o]; viv = pvi[o]; fuv = pfu[o];
            }

            // ---- horizontal 9-tap (center + 4 symmetric pairs) ----
            float t_i = irv - fuv, t_v = viv - fuv;
            float hbi  = t_i * t_i;
            float hbv  = t_v * t_v;
            float hgi  = g4 * irv;
            float hgv  = g4 * viv;
            float hg2i = g4 * (irv * irv);
            float hg2v = g4 * (viv * viv);
            #pragma unroll
            for (int k = 1; k <= 4; ++k) {
                const float gk = gw.g[4 - k];
                float irm = __int_as_float(__builtin_amdgcn_ds_bpermute(bpm[k-1], __float_as_int(irv)));
                float irp = __int_as_float(__builtin_amdgcn_ds_bpermute(bpp[k-1], __float_as_int(irv)));
                float vim = __int_as_float(__builtin_amdgcn_ds_bpermute(bpm[k-1], __float_as_int(viv)));
                float vip = __int_as_float(__builtin_amdgcn_ds_bpermute(bpp[k-1], __float_as_int(viv)));
                float fum = __int_as_float(__builtin_amdgcn_ds_bpermute(bpm[k-1], __float_as_int(fuv)));
                float fup = __int_as_float(__builtin_amdgcn_ds_bpermute(bpp[k-1], __float_as_int(fuv)));
                float a = irm - fum, b = irp - fup;
                hbi = fmaf(a, a, hbi); hbi = fmaf(b, b, hbi);
                float c = vim - fum, d = vip - fup;
                hbv = fmaf(c, c, hbv); hbv = fmaf(d, d, hbv);
                hgi  = fmaf(gk, irm + irp, hgi);
                hgv  = fmaf(gk, vim + vip, hgv);
                hg2i = fmaf(gk, fmaf(irm, irm, irp * irp), hg2i);
                hg2v = fmaf(gk, fmaf(vim, vim, vip * vip), hg2v);
            }

            // ---- vertical: box rolling window (rows r-8..r) ----
            Sb_i += hbi - hb_i[j];  hb_i[j] = hbi;
            Sb_v += hbv - hb_v[j];  hb_v[j] = hbv;

            // ---- vertical: gauss accumulate into 8 pending slots ----
            #pragma unroll
            for (int s = 0; s < 9; ++s) {
                if (s == j) continue;
                const float gws = gw.g[(j - s - 1 + 9) % 9];   // compile-time
                ag_ir[s] = fmaf(gws, hgi,  ag_ir[s]);
                ag_vi[s] = fmaf(gws, hgv,  ag_vi[s]);
                ag_i2[s] = fmaf(gws, hg2i, ag_i2[s]);
                ag_v2[s] = fmaf(gws, hg2v, ag_v2[s]);
            }
            // slot j completes with this row's g[8] contribution
            float mu_i = fmaf(g8, hgi,  ag_ir[j]);
            float mu_v = fmaf(g8, hgv,  ag_vi[j]);
            float m2i  = fmaf(g8, hg2i, ag_i2[j]);
            float m2v  = fmaf(g8, hg2v, ag_v2[j]);
            ag_ir[j] = 0.f; ag_vi[j] = 0.f; ag_i2[j] = 0.f; ag_v2[j] = 0.f;

            if (emit) {
                float var_i = m2i - mu_i * mu_i;
                float var_v = m2v - mu_v * mu_v;
                float mse_i = Sb_i * (1.f / 81.f);
                float mse_v = Sb_v * (1.f / 81.f);
                float m1  = (var_i - var_v > 0.f) ? 1.f : 0.f;
                float sel = (m1 + mkv > 0.f) ? 1.f : 0.f;
                float res = sel * mse_i + (1.f - sel) * mse_v;
                if (oklane) acc += res;
            }
        }
    }

    // wave reduction + one atomic per wave (2560 total)
    #pragma unroll
    for (int off = 32; off > 0; off >>= 1)
        acc += __shfl_down(acc, off, 64);
    if (lane == 0)
        atomicAdd(out, acc * (1.f / 8388608.f));   // 1/(32*512*512)
}

extern "C" void kernel_launch(void* const* d_in, const int* in_sizes, int n_in,
                              void* d_out, int out_size, void* d_ws, size_t ws_size,
                              hipStream_t stream) {
    const float* vis  = (const float*)d_in[0];
    const float* ir   = (const float*)d_in[1];
    const float* fus  = (const float*)d_in[2];
    const float* mask = (const float*)d_in[3];
    float* out = (float*)d_out;

    GaussW gw;
    double g[9], s = 0.0;
    for (int i = 0; i < 9; ++i) {
        int x = i - 4;
        g[i] = exp(-(double)(x * x) / 4.5);
        s += g[i];
    }
    for (int i = 0; i < 9; ++i) gw.g[i] = (float)(g[i] / s);

    hipMemsetAsync(d_out, 0, sizeof(float), stream);
    fuse_loss_kernel<<<NBLK, 256, 0, stream>>>(vis, ir, fus, mask, out, gw);
}

// Round 7
// 109.576 us; speedup vs baseline: 1.2286x; 1.2286x over previous
//
#include <hip/hip_runtime.h>
#include <cmath>

#define Bn 32
#define Hn 512
#define Wn 512
#define PADn 4
#define TW 32
#define TH 32
#define RW (TW + 8)   // 40
#define RH (TH + 8)   // 40
#define NTILES (Bn * (Hn / TH) * (Wn / TW))   // 8192
#define NBLK 1024                              // persistent blocks; 8 tiles each

struct GaussW { float g[9]; };

// Persistent-block tiled separable conv. R5 showed per-tile pipeline works
// (6.8us/tile, 92 VGPR no spill) but 8192 short blocks were throughput-pinned
// at ~61 wg/us (CP dispatch rate and/or the 8192-deep same-address atomicAdd
// chain). Fix both: 1024 resident blocks (4/CU) x 8 tiles each, register
// accumulation, per-block partial to d_ws, separate 1-block reduce kernel.
__global__ __launch_bounds__(256, 2) void fuse_loss_kernel(
    const float* __restrict__ vis, const float* __restrict__ ir,
    const float* __restrict__ fus, const float* __restrict__ mask,
    float* __restrict__ ws, GaussW gw)
{
    // Union LDS: phase A/B use s_in[40][40] float4 (25600 B); after a barrier
    // reused as s_h1[40][32] float4 (20480 B) + s_h2[40][32] float2 (10240 B).
    __shared__ float4 s_buf[1920];          // 30720 B
    float4* s_in = s_buf;                   // [RH][RW]
    float4* s_h1 = s_buf;                   // [RH][TW]
    float2* s_h2 = (float2*)(s_buf + 1280); // [RH][TW]
    __shared__ float s_part[4];

    const int t  = threadIdx.x;
    const int cx = t & 31;      // column owned by this thread (phases B & C)
    const int r0 = t >> 5;      // base row

    float acc = 0.f;            // across all tiles this block owns

    for (int tile = blockIdx.x; tile < NTILES; tile += NBLK) {
        const int img = tile >> 8;          // 256 tiles per image
        const int rem = tile & 255;
        const int y0 = (rem >> 4) * TH;
        const int x0 = (rem & 15) * TW;
        const size_t base = (size_t)img * (size_t)(Hn * Wn);

        // ---- Phase A: stage halo region (zero padding outside image) ----
        for (int idx = t; idx < RH * RW; idx += 256) {
            int ry = idx / RW, rx = idx - ry * RW;
            int gy = y0 + ry - PADn, gx = x0 + rx - PADn;
            float4 v = make_float4(0.f, 0.f, 0.f, 0.f);
            if ((unsigned)gy < (unsigned)Hn && (unsigned)gx < (unsigned)Wn) {
                size_t o = base + (size_t)gy * Wn + gx;
                v.x = ir[o]; v.y = vis[o]; v.z = fus[o];
            }
            s_in[idx] = v;
        }

        // prefetch mask for this thread's 4 output pixels (overlaps staging)
        float mk[4];
        #pragma unroll
        for (int k = 0; k < 4; ++k) {
            int ty = r0 + 8 * k;
            mk[k] = mask[base + (size_t)(y0 + ty) * Wn + (x0 + cx)];
        }
        __syncthreads();

        // ---- Phase B: horizontal 9-tap pass, results in registers ----
        float r_hb_ir[5], r_hb_vi[5], r_hg_ir[5], r_hg_vi[5], r_hg_i2[5], r_hg_v2[5];
        #pragma unroll
        for (int k = 0; k < 5; ++k) {
            int ry = r0 + 8 * k;
            float hb_ir = 0.f, hb_vi = 0.f;
            float hg_ir = 0.f, hg_vi = 0.f, hg_i2 = 0.f, hg_v2 = 0.f;
            #pragma unroll
            for (int dx = 0; dx < 9; ++dx) {
                float4 v = s_in[ry * RW + cx + dx];
                float di = v.x - v.z;
                float dv = v.y - v.z;
                hb_ir = fmaf(di, di, hb_ir);
                hb_vi = fmaf(dv, dv, hb_vi);
                float g = gw.g[dx];
                hg_ir = fmaf(g, v.x, hg_ir);
                hg_vi = fmaf(g, v.y, hg_vi);
                hg_i2 = fmaf(g, v.x * v.x, hg_i2);
                hg_v2 = fmaf(g, v.y * v.y, hg_v2);
            }
            r_hb_ir[k] = hb_ir; r_hb_vi[k] = hb_vi;
            r_hg_ir[k] = hg_ir; r_hg_vi[k] = hg_vi;
            r_hg_i2[k] = hg_i2; r_hg_v2[k] = hg_v2;
        }
        __syncthreads();   // all s_in reads complete -> safe to overwrite

        #pragma unroll
        for (int k = 0; k < 5; ++k) {
            int ry = r0 + 8 * k;
            s_h1[ry * TW + cx] = make_float4(r_hb_ir[k], r_hb_vi[k], r_hg_ir[k], r_hg_vi[k]);
            s_h2[ry * TW + cx] = make_float2(r_hg_i2[k], r_hg_v2[k]);
        }
        __syncthreads();

        // ---- Phase C: vertical 9-tap pass + selection + accumulate ----
        #pragma unroll
        for (int k = 0; k < 4; ++k) {
            int ty = r0 + 8 * k;
            float b_ir = 0.f, b_vi = 0.f;
            float mu_ir = 0.f, mu_vi = 0.f, m2_ir = 0.f, m2_vi = 0.f;
            #pragma unroll
            for (int dy = 0; dy < 9; ++dy) {
                float4 h1 = s_h1[(ty + dy) * TW + cx];
                float2 h2 = s_h2[(ty + dy) * TW + cx];
                b_ir += h1.x;
                b_vi += h1.y;
                float g = gw.g[dy];
                mu_ir = fmaf(g, h1.z, mu_ir);
                mu_vi = fmaf(g, h1.w, mu_vi);
                m2_ir = fmaf(g, h2.x, m2_ir);
                m2_vi = fmaf(g, h2.y, m2_vi);
            }
            float mse_ir = b_ir * (1.f / 81.f);
            float mse_vi = b_vi * (1.f / 81.f);
            float var_ir = m2_ir - mu_ir * mu_ir;
            float var_vi = m2_vi - mu_vi * mu_vi;
            float m1 = (var_ir - var_vi > 0.f) ? 1.f : 0.f;
            float mir = (m1 + mk[k] > 0.f) ? 1.f : 0.f;
            acc += mir * mse_ir + (1.f - mir) * mse_vi;
        }
        __syncthreads();   // s_h reads done -> next tile may overwrite s_in
    }

    // ---- one partial per block, no atomics ----
    #pragma unroll
    for (int off = 32; off > 0; off >>= 1)
        acc += __shfl_down(acc, off, 64);
    int wave = t >> 6, lane = t & 63;
    if (lane == 0) s_part[wave] = acc;
    __syncthreads();
    if (t == 0)
        ws[blockIdx.x] = s_part[0] + s_part[1] + s_part[2] + s_part[3];
}

__global__ __launch_bounds__(256) void reduce_kernel(const float* __restrict__ ws,
                                                     float* __restrict__ out)
{
    __shared__ float sp[4];
    int t = threadIdx.x;
    float v = 0.f;
    for (int i = t; i < NBLK; i += 256) v += ws[i];
    #pragma unroll
    for (int off = 32; off > 0; off >>= 1)
        v += __shfl_down(v, off, 64);
    if ((t & 63) == 0) sp[t >> 6] = v;
    __syncthreads();
    if (t == 0)
        out[0] = (sp[0] + sp[1] + sp[2] + sp[3]) * (1.f / ((float)Bn * Hn * Wn));
}

extern "C" void kernel_launch(void* const* d_in, const int* in_sizes, int n_in,
                              void* d_out, int out_size, void* d_ws, size_t ws_size,
                              hipStream_t stream) {
    const float* vis  = (const float*)d_in[0];
    const float* ir   = (const float*)d_in[1];
    const float* fus  = (const float*)d_in[2];
    const float* mask = (const float*)d_in[3];
    float* out = (float*)d_out;
    float* ws  = (float*)d_ws;

    GaussW gw;
    double g[9], s = 0.0;
    for (int i = 0; i < 9; ++i) {
        int x = i - 4;
        g[i] = exp(-(double)(x * x) / 4.5);
        s += g[i];
    }
    for (int i = 0; i < 9; ++i) gw.g[i] = (float)(g[i] / s);

    fuse_loss_kernel<<<NBLK, 256, 0, stream>>>(vis, ir, fus, mask, ws, gw);
    reduce_kernel<<<1, 256, 0, stream>>>(ws, out);
}

// Round 8
// 91.328 us; speedup vs baseline: 1.4741x; 1.1998x over previous
//
#include <hip/hip_runtime.h>
#include <cmath>

#define Bn 32
#define Hn 512
#define Wn 512
#define PADn 4
#define TW 32
#define TH 32
#define RW (TW + 8)   // 40
#define RH (TH + 8)   // 40
#define NPTS (RH * RW)                         // 1600 staged points
#define NTILES (Bn * (Hn / TH) * (Wn / TW))   // 8192
#define NBLK 1024                              // persistent blocks; 8 tiles each

struct GaussW { float g[9]; };

// Persistent-block tiled separable conv with issue-early phase A.
// R7 analysis: per-tile 6.8us was dominated by 7 serial load->ds_write
// rounds in the staging loop (~900cy HBM latency each, loop-carried).
// Fix: fully unroll staging into 21 predicated scalar loads issued
// back-to-back (one latency), then store all to LDS after one wait.
__global__ __launch_bounds__(256, 2) void fuse_loss_kernel(
    const float* __restrict__ vis, const float* __restrict__ ir,
    const float* __restrict__ fus, const float* __restrict__ mask,
    float* __restrict__ ws, GaussW gw)
{
    // Union LDS: phase A/B use s_in[40][40] float4 (25600 B); after a barrier
    // reused as s_h1[40][32] float4 (20480 B) + s_h2[40][32] float2 (10240 B).
    __shared__ float4 s_buf[1920];          // 30720 B
    float4* s_in = s_buf;                   // [RH][RW]
    float4* s_h1 = s_buf;                   // [RH][TW]
    float2* s_h2 = (float2*)(s_buf + 1280); // [RH][TW]
    __shared__ float s_part[4];

    const int t  = threadIdx.x;
    const int cx = t & 31;      // column owned by this thread (phases B & C)
    const int r0 = t >> 5;      // base row

    float acc = 0.f;            // across all tiles this block owns

    for (int tile = blockIdx.x; tile < NTILES; tile += NBLK) {
        const int img = tile >> 8;          // 256 tiles per image
        const int rem = tile & 255;
        const int y0 = (rem >> 4) * TH;
        const int x0 = (rem & 15) * TW;
        const size_t base = (size_t)img * (size_t)(Hn * Wn);

        // ---- Phase A: issue-early register staging (21 loads in flight) ----
        float vir[7], vvi[7], vfu[7];
        bool  okf[7];
        #pragma unroll
        for (int r = 0; r < 7; ++r) {
            int idx = t + 256 * r;
            int ry = idx / RW, rx = idx - ry * RW;
            int gy = y0 + ry - PADn, gx = x0 + rx - PADn;
            bool ok = (idx < NPTS) &&
                      ((unsigned)gy < (unsigned)Hn) && ((unsigned)gx < (unsigned)Wn);
            size_t o = ok ? (base + (size_t)gy * Wn + gx) : 0;
            vir[r] = ir[o];            // predicated via clamped addr + select
            vvi[r] = vis[o];
            vfu[r] = fus[o];
            okf[r] = ok;
        }
        // prefetch mask for this thread's 4 output pixels (also in flight)
        float mk[4];
        #pragma unroll
        for (int k = 0; k < 4; ++k) {
            int ty = r0 + 8 * k;
            mk[k] = mask[base + (size_t)(y0 + ty) * Wn + (x0 + cx)];
        }
        // write-late: one waitcnt, then stream all stores to LDS
        #pragma unroll
        for (int r = 0; r < 7; ++r) {
            int idx = t + 256 * r;
            if (idx < NPTS) {
                float4 v = okf[r] ? make_float4(vir[r], vvi[r], vfu[r], 0.f)
                                  : make_float4(0.f, 0.f, 0.f, 0.f);
                s_in[idx] = v;
            }
        }
        __syncthreads();

        // ---- Phase B: horizontal 9-tap pass, results in registers ----
        float r_hb_ir[5], r_hb_vi[5], r_hg_ir[5], r_hg_vi[5], r_hg_i2[5], r_hg_v2[5];
        #pragma unroll
        for (int k = 0; k < 5; ++k) {
            int ry = r0 + 8 * k;
            float hb_ir = 0.f, hb_vi = 0.f;
            float hg_ir = 0.f, hg_vi = 0.f, hg_i2 = 0.f, hg_v2 = 0.f;
            #pragma unroll
            for (int dx = 0; dx < 9; ++dx) {
                float4 v = s_in[ry * RW + cx + dx];
                float di = v.x - v.z;
                float dv = v.y - v.z;
                hb_ir = fmaf(di, di, hb_ir);
                hb_vi = fmaf(dv, dv, hb_vi);
                float g = gw.g[dx];
                hg_ir = fmaf(g, v.x, hg_ir);
                hg_vi = fmaf(g, v.y, hg_vi);
                hg_i2 = fmaf(g, v.x * v.x, hg_i2);
                hg_v2 = fmaf(g, v.y * v.y, hg_v2);
            }
            r_hb_ir[k] = hb_ir; r_hb_vi[k] = hb_vi;
            r_hg_ir[k] = hg_ir; r_hg_vi[k] = hg_vi;
            r_hg_i2[k] = hg_i2; r_hg_v2[k] = hg_v2;
        }
        __syncthreads();   // all s_in reads complete -> safe to overwrite

        #pragma unroll
        for (int k = 0; k < 5; ++k) {
            int ry = r0 + 8 * k;
            s_h1[ry * TW + cx] = make_float4(r_hb_ir[k], r_hb_vi[k], r_hg_ir[k], r_hg_vi[k]);
            s_h2[ry * TW + cx] = make_float2(r_hg_i2[k], r_hg_v2[k]);
        }
        __syncthreads();

        // ---- Phase C: vertical 9-tap pass + selection + accumulate ----
        #pragma unroll
        for (int k = 0; k < 4; ++k) {
            int ty = r0 + 8 * k;
            float b_ir = 0.f, b_vi = 0.f;
            float mu_ir = 0.f, mu_vi = 0.f, m2_ir = 0.f, m2_vi = 0.f;
            #pragma unroll
            for (int dy = 0; dy < 9; ++dy) {
                float4 h1 = s_h1[(ty + dy) * TW + cx];
                float2 h2 = s_h2[(ty + dy) * TW + cx];
                b_ir += h1.x;
                b_vi += h1.y;
                float g = gw.g[dy];
                mu_ir = fmaf(g, h1.z, mu_ir);
                mu_vi = fmaf(g, h1.w, mu_vi);
                m2_ir = fmaf(g, h2.x, m2_ir);
                m2_vi = fmaf(g, h2.y, m2_vi);
            }
            float mse_ir = b_ir * (1.f / 81.f);
            float mse_vi = b_vi * (1.f / 81.f);
            float var_ir = m2_ir - mu_ir * mu_ir;
            float var_vi = m2_vi - mu_vi * mu_vi;
            float m1 = (var_ir - var_vi > 0.f) ? 1.f : 0.f;
            float mir = (m1 + mk[k] > 0.f) ? 1.f : 0.f;
            acc += mir * mse_ir + (1.f - mir) * mse_vi;
        }
        __syncthreads();   // s_h reads done -> next tile may overwrite s_in
    }

    // ---- one partial per block, no atomics ----
    #pragma unroll
    for (int off = 32; off > 0; off >>= 1)
        acc += __shfl_down(acc, off, 64);
    int wave = t >> 6, lane = t & 63;
    if (lane == 0) s_part[wave] = acc;
    __syncthreads();
    if (t == 0)
        ws[blockIdx.x] = s_part[0] + s_part[1] + s_part[2] + s_part[3];
}

__global__ __launch_bounds__(256) void reduce_kernel(const float* __restrict__ ws,
                                                     float* __restrict__ out)
{
    __shared__ float sp[4];
    int t = threadIdx.x;
    float v = 0.f;
    for (int i = t; i < NBLK; i += 256) v += ws[i];
    #pragma unroll
    for (int off = 32; off > 0; off >>= 1)
        v += __shfl_down(v, off, 64);
    if ((t & 63) == 0) sp[t >> 6] = v;
    __syncthreads();
    if (t == 0)
        out[0] = (sp[0] + sp[1] + sp[2] + sp[3]) * (1.f / ((float)Bn * Hn * Wn));
}

extern "C" void kernel_launch(void* const* d_in, const int* in_sizes, int n_in,
                              void* d_out, int out_size, void* d_ws, size_t ws_size,
                              hipStream_t stream) {
    const float* vis  = (const float*)d_in[0];
    const float* ir   = (const float*)d_in[1];
    const float* fus  = (const float*)d_in[2];
    const float* mask = (const float*)d_in[3];
    float* out = (float*)d_out;
    float* ws  = (float*)d_ws;

    GaussW gw;
    double g[9], s = 0.0;
    for (int i = 0; i < 9; ++i) {
        int x = i - 4;
        g[i] = exp(-(double)(x * x) / 4.5);
        s += g[i];
    }
    for (int i = 0; i < 9; ++i) gw.g[i] = (float)(g[i] / s);

    fuse_loss_kernel<<<NBLK, 256, 0, stream>>>(vis, ir, fus, mask, ws, gw);
    reduce_kernel<<<1, 256, 0, stream>>>(ws, out);
}